// Round 1
// baseline (1961.462 us; speedup 1.0000x reference)
//
#include <hip/hip_runtime.h>

#define NEG_SLOPE 0.2f

// ---------------- Kernel 1: node prep layer 1 ----------------
// h1[i,j] = xin[i,:21] @ W1[:,j];  als1[i,h] = sum_c h1[i,h*32+c]*a_src1[h,c]; ald1 likewise.
// 256 threads = 4 nodes x 64 lanes.
__global__ void k_node1(const float* __restrict__ x, const int* __restrict__ type_ids,
                        const float* __restrict__ type_emb, const float* __restrict__ W1,
                        const float* __restrict__ a_src1, const float* __restrict__ a_dst1,
                        float* __restrict__ h1, float* __restrict__ als1, float* __restrict__ ald1,
                        int N)
{
    int node = blockIdx.x * 4 + (threadIdx.x >> 6);
    int j = threadIdx.x & 63;
    if (node >= N) return;

    float xin[21];
#pragma unroll
    for (int k = 0; k < 5; k++) xin[k] = x[node * 5 + k];
    int t = type_ids[node];
#pragma unroll
    for (int k = 0; k < 16; k++) xin[5 + k] = type_emb[t * 16 + k];

    float h = 0.f;
#pragma unroll
    for (int k = 0; k < 21; k++) h += xin[k] * W1[k * 64 + j];
    h1[node * 64 + j] = h;

    int head = j >> 5, lane = j & 31;
    float ps = h * a_src1[head * 32 + lane];
    float pd = h * a_dst1[head * 32 + lane];
#pragma unroll
    for (int m = 16; m >= 1; m >>= 1) { ps += __shfl_xor(ps, m); pd += __shfl_xor(pd, m); }
    if (lane == 0) { als1[node * 2 + head] = ps; ald1[node * 2 + head] = pd; }
}

// ---------------- Kernel 2: edge pass layer 1 ----------------
// One wave per edge (incl. self-loops). lane c accumulates num1[d*64+c] += w_h * h1[s*64+c].
__global__ void k_edge1(const int* __restrict__ ei, const float* __restrict__ h1,
                        const float* __restrict__ als1, const float* __restrict__ ald1,
                        float* __restrict__ num1, float* __restrict__ den1,
                        int E, int EV)
{
    int e = blockIdx.x * 4 + (threadIdx.x >> 6);
    if (e >= EV) return;
    int c = threadIdx.x & 63;
    int s, d;
    if (e < E) { s = ei[e]; d = ei[E + e]; } else { s = e - E; d = s; }
    int head = c >> 5;
    float l = als1[s * 2 + head] + ald1[d * 2 + head];
    l = (l >= 0.f) ? l : NEG_SLOPE * l;
    float w = expf(l);
    atomicAdd(&num1[(size_t)d * 64 + c], w * h1[(size_t)s * 64 + c]);
    if ((c & 31) == 0) atomicAdd(&den1[d * 2 + head], w);
}

// ---------------- Kernel 3: finish layer 1, project W2, layer-2 logits ----------------
// h2 = relu(num1/den1 + b1) (LDS only); h3 = h2 @ W2; als2/ald2 = h3 . a2
__global__ void k_node2(const float* __restrict__ num1, const float* __restrict__ den1,
                        const float* __restrict__ b1, const float* __restrict__ W2,
                        const float* __restrict__ a_src2, const float* __restrict__ a_dst2,
                        float* __restrict__ h3, float* __restrict__ als2, float* __restrict__ ald2,
                        int N)
{
    __shared__ float sh[4][64];
    int g = threadIdx.x >> 6;
    int node = blockIdx.x * 4 + g;
    int j = threadIdx.x & 63;

    float h2 = 0.f;
    if (node < N) {
        int head = j >> 5;
        float den = den1[node * 2 + head];
        h2 = num1[(size_t)node * 64 + j] / (den + 1e-16f) + b1[j];
        h2 = fmaxf(h2, 0.f);
    }
    sh[g][j] = h2;
    __syncthreads();
    if (node >= N) return;

    float acc = 0.f;
#pragma unroll
    for (int k = 0; k < 64; k++) acc += sh[g][k] * W2[k * 64 + j];
    h3[(size_t)node * 64 + j] = acc;

    float ps = acc * a_src2[j];
    float pd = acc * a_dst2[j];
#pragma unroll
    for (int m = 32; m >= 1; m >>= 1) { ps += __shfl_xor(ps, m); pd += __shfl_xor(pd, m); }
    if (j == 0) { als2[node] = ps; ald2[node] = pd; }
}

// ---------------- Kernel 4: edge pass layer 2 (1 head, 64 ch) ----------------
__global__ void k_edge2(const int* __restrict__ ei, const float* __restrict__ h3,
                        const float* __restrict__ als2, const float* __restrict__ ald2,
                        float* __restrict__ num2, float* __restrict__ den2,
                        int E, int EV)
{
    int e = blockIdx.x * 4 + (threadIdx.x >> 6);
    if (e >= EV) return;
    int c = threadIdx.x & 63;
    int s, d;
    if (e < E) { s = ei[e]; d = ei[E + e]; } else { s = e - E; d = s; }
    float l = als2[s] + ald2[d];
    l = (l >= 0.f) ? l : NEG_SLOPE * l;
    float w = expf(l);
    atomicAdd(&num2[(size_t)d * 64 + c], w * h3[(size_t)s * 64 + c]);
    if (c == 0) atomicAdd(&den2[d], w);
}

// ---------------- Kernel 5: finish layer 2 + LayerNorm ----------------
__global__ void k_out(const float* __restrict__ num2, const float* __restrict__ den2,
                      const float* __restrict__ b2, const float* __restrict__ gamma,
                      const float* __restrict__ beta, float* __restrict__ out, int N)
{
    int node = blockIdx.x * 4 + (threadIdx.x >> 6);
    int j = threadIdx.x & 63;
    if (node >= N) return;
    float o = num2[(size_t)node * 64 + j] / (den2[node] + 1e-16f) + b2[j];
    float s = o;
#pragma unroll
    for (int m = 32; m >= 1; m >>= 1) s += __shfl_xor(s, m);
    float mu = s * (1.f / 64.f);
    float dv = o - mu;
    float v = dv * dv;
#pragma unroll
    for (int m = 32; m >= 1; m >>= 1) v += __shfl_xor(v, m);
    v *= (1.f / 64.f);
    out[(size_t)node * 64 + j] = dv * rsqrtf(v + 1e-5f) * gamma[j] + beta[j];
}

extern "C" void kernel_launch(void* const* d_in, const int* in_sizes, int n_in,
                              void* d_out, int out_size, void* d_ws, size_t ws_size,
                              hipStream_t stream) {
    const float* x        = (const float*)d_in[0];
    const int*   ei       = (const int*)  d_in[1];
    const int*   type_ids = (const int*)  d_in[2];
    const float* type_emb = (const float*)d_in[3];
    const float* W1       = (const float*)d_in[4];
    const float* a_src1   = (const float*)d_in[5];
    const float* a_dst1   = (const float*)d_in[6];
    const float* b1       = (const float*)d_in[7];
    const float* W2       = (const float*)d_in[8];
    const float* a_src2   = (const float*)d_in[9];
    const float* a_dst2   = (const float*)d_in[10];
    const float* b2       = (const float*)d_in[11];
    const float* gamma    = (const float*)d_in[12];
    const float* beta     = (const float*)d_in[13];

    int N = in_sizes[0] / 5;
    int E = in_sizes[1] / 2;
    int EV = E + N;  // edges + self-loops

    float* ws   = (float*)d_ws;
    float* bufA = ws;                         // h1, later h3    [N*64]
    float* bufB = bufA + (size_t)N * 64;      // num1, later num2 [N*64]
    float* als1 = bufB + (size_t)N * 64;      // [N*2]
    float* ald1 = als1 + (size_t)N * 2;       // [N*2]
    float* den1 = ald1 + (size_t)N * 2;       // [N*2]
    float* als2 = den1 + (size_t)N * 2;       // [N]
    float* ald2 = als2 + (size_t)N;           // [N]
    float* den2 = ald2 + (size_t)N;           // [N]

    dim3 tb(256);
    dim3 nb((N + 3) / 4);
    dim3 eb((EV + 3) / 4);

    // Layer 1
    hipMemsetAsync(bufB, 0, (size_t)N * 64 * sizeof(float), stream);
    hipMemsetAsync(den1, 0, (size_t)N * 2 * sizeof(float), stream);
    k_node1<<<nb, tb, 0, stream>>>(x, type_ids, type_emb, W1, a_src1, a_dst1,
                                   bufA, als1, ald1, N);
    k_edge1<<<eb, tb, 0, stream>>>(ei, bufA, als1, ald1, bufB, den1, E, EV);
    k_node2<<<nb, tb, 0, stream>>>(bufB, den1, b1, W2, a_src2, a_dst2,
                                   bufA, als2, ald2, N);

    // Layer 2 (reuse bufB as num2 — stream order guarantees k_node2 done first)
    hipMemsetAsync(bufB, 0, (size_t)N * 64 * sizeof(float), stream);
    hipMemsetAsync(den2, 0, (size_t)N * sizeof(float), stream);
    k_edge2<<<eb, tb, 0, stream>>>(ei, bufA, als2, ald2, bufB, den2, E, EV);
    k_out<<<nb, tb, 0, stream>>>(bufB, den2, b2, gamma, beta, (float*)d_out, N);
}

// Round 2
// 974.917 us; speedup vs baseline: 2.0119x; 2.0119x over previous
//
#include <hip/hip_runtime.h>

#define NEG_SLOPE 0.2f

// ---------------- Kernel: node prep layer 1 ----------------
// h1[i,j] = xin[i,:21] @ W1[:,j];  als1/ald1[i,h] = h1[i,h*32+:] . a_{src,dst}1[h,:]
__global__ void k_node1(const float* __restrict__ x, const int* __restrict__ type_ids,
                        const float* __restrict__ type_emb, const float* __restrict__ W1,
                        const float* __restrict__ a_src1, const float* __restrict__ a_dst1,
                        float* __restrict__ h1, float* __restrict__ als1, float* __restrict__ ald1,
                        int N)
{
    int node = blockIdx.x * 4 + (threadIdx.x >> 6);
    int j = threadIdx.x & 63;
    if (node >= N) return;

    float xin[21];
#pragma unroll
    for (int k = 0; k < 5; k++) xin[k] = x[node * 5 + k];
    int t = type_ids[node];
#pragma unroll
    for (int k = 0; k < 16; k++) xin[5 + k] = type_emb[t * 16 + k];

    float h = 0.f;
#pragma unroll
    for (int k = 0; k < 21; k++) h += xin[k] * W1[k * 64 + j];
    h1[node * 64 + j] = h;

    int head = j >> 5, lane = j & 31;
    float ps = h * a_src1[head * 32 + lane];
    float pd = h * a_dst1[head * 32 + lane];
#pragma unroll
    for (int m = 16; m >= 1; m >>= 1) { ps += __shfl_xor(ps, m); pd += __shfl_xor(pd, m); }
    if (lane == 0) { als1[node * 2 + head] = ps; ald1[node * 2 + head] = pd; }
}

// ---------------- CSR build ----------------
__global__ void k_initdeg(int* __restrict__ deg, int N) {
    int i = blockIdx.x * 256 + threadIdx.x;
    if (i < N) deg[i] = 1;  // self-loop
}

__global__ void k_hist(const int* __restrict__ ei, int* __restrict__ deg, int E) {
    int i = blockIdx.x * 256 + threadIdx.x;
    if (i < E) atomicAdd(&deg[ei[E + i]], 1);
}

// per-1024-chunk exclusive scan + block sums (Hillis-Steele in LDS)
__global__ void k_scan_block(const int* __restrict__ deg, int* __restrict__ rs,
                             int* __restrict__ bsum, int N) {
    __shared__ int sh[1024];
    int t = threadIdx.x;
    int i = blockIdx.x * 1024 + t;
    int v = (i < N) ? deg[i] : 0;
    sh[t] = v;
    __syncthreads();
    for (int off = 1; off < 1024; off <<= 1) {
        int xv = (t >= off) ? sh[t - off] : 0;
        __syncthreads();
        sh[t] += xv;
        __syncthreads();
    }
    if (i < N) rs[i] = sh[t] - v;               // exclusive
    if (t == 1023) bsum[blockIdx.x] = sh[1023]; // block total
}

__global__ void k_scan_tops(int* __restrict__ bsum, int* __restrict__ btop, int NB) {
    __shared__ int sh[1024];
    int t = threadIdx.x;
    int v = (t < NB) ? bsum[t] : 0;
    sh[t] = v;
    __syncthreads();
    for (int off = 1; off < 1024; off <<= 1) {
        int xv = (t >= off) ? sh[t - off] : 0;
        __syncthreads();
        sh[t] += xv;
        __syncthreads();
    }
    if (t < NB) btop[t] = sh[t] - v; // exclusive
}

__global__ void k_scan_add(int* __restrict__ rs, int* __restrict__ cur,
                           const int* __restrict__ btop, int N) {
    int i = blockIdx.x * 256 + threadIdx.x;
    if (i < N) {
        int r = rs[i] + btop[i >> 10];
        rs[i] = r;
        cur[i] = r;
    }
}

__global__ void k_scatter(const int* __restrict__ ei, int* __restrict__ cur,
                          int* __restrict__ ssrc, int E, int N) {
    int i = blockIdx.x * 256 + threadIdx.x;
    if (i < E) {
        int d = ei[E + i];
        int p = atomicAdd(&cur[d], 1);
        ssrc[p] = ei[i];
    } else if (i < E + N) {
        int d = i - E;
        int p = atomicAdd(&cur[d], 1);
        ssrc[p] = d; // self-loop
    }
}
// After k_scatter: cur[d] == rs[d] + deg[d] == row end.

// ---------------- Gather layer 1 (2 heads x 32 ch) ----------------
// One wave per dst node; lane = channel. Fuses softmax div + b1 + relu -> h2.
__global__ void k_gather1(const int* __restrict__ rs, const int* __restrict__ cur,
                          const int* __restrict__ ssrc, const float* __restrict__ h1,
                          const float* __restrict__ als1, const float* __restrict__ ald1,
                          const float* __restrict__ b1, float* __restrict__ h2, int N)
{
    int node = blockIdx.x * 4 + (threadIdx.x >> 6);
    if (node >= N) return;
    int c = threadIdx.x & 63;
    int head = c >> 5;
    float ad = ald1[node * 2 + head];

    int beg = rs[node], end = cur[node];
    float acc = 0.f, wsum = 0.f;
    int i = beg;
    for (; i + 1 < end; i += 2) {
        int s0 = ssrc[i], s1 = ssrc[i + 1];
        float l0 = als1[s0 * 2 + head] + ad;
        float l1 = als1[s1 * 2 + head] + ad;
        float hv0 = h1[s0 * 64 + c];
        float hv1 = h1[s1 * 64 + c];
        l0 = (l0 >= 0.f) ? l0 : NEG_SLOPE * l0;
        l1 = (l1 >= 0.f) ? l1 : NEG_SLOPE * l1;
        float w0 = __expf(l0), w1 = __expf(l1);
        acc += w0 * hv0; wsum += w0;
        acc += w1 * hv1; wsum += w1;
    }
    if (i < end) {
        int s0 = ssrc[i];
        float l0 = als1[s0 * 2 + head] + ad;
        float hv0 = h1[s0 * 64 + c];
        l0 = (l0 >= 0.f) ? l0 : NEG_SLOPE * l0;
        float w0 = __expf(l0);
        acc += w0 * hv0; wsum += w0;
    }
    float v = acc / (wsum + 1e-16f) + b1[c];
    h2[(size_t)node * 64 + c] = fmaxf(v, 0.f);
}

// ---------------- Node kernel 2: h3 = h2 @ W2, layer-2 logits ----------------
__global__ void k_node2(const float* __restrict__ h2, const float* __restrict__ W2,
                        const float* __restrict__ a_src2, const float* __restrict__ a_dst2,
                        float* __restrict__ h3, float* __restrict__ als2, float* __restrict__ ald2,
                        int N)
{
    __shared__ float sh[4][64];
    int g = threadIdx.x >> 6;
    int node = blockIdx.x * 4 + g;
    int j = threadIdx.x & 63;

    float hv = (node < N) ? h2[(size_t)node * 64 + j] : 0.f;
    sh[g][j] = hv;
    __syncthreads();
    if (node >= N) return;

    float acc = 0.f;
#pragma unroll
    for (int k = 0; k < 64; k++) acc += sh[g][k] * W2[k * 64 + j];
    h3[(size_t)node * 64 + j] = acc;

    float ps = acc * a_src2[j];
    float pd = acc * a_dst2[j];
#pragma unroll
    for (int m = 32; m >= 1; m >>= 1) { ps += __shfl_xor(ps, m); pd += __shfl_xor(pd, m); }
    if (j == 0) { als2[node] = ps; ald2[node] = pd; }
}

// ---------------- Gather layer 2 (1 head, 64 ch) + LayerNorm ----------------
__global__ void k_gather2(const int* __restrict__ rs, const int* __restrict__ cur,
                          const int* __restrict__ ssrc, const float* __restrict__ h3,
                          const float* __restrict__ als2, const float* __restrict__ ald2,
                          const float* __restrict__ b2, const float* __restrict__ gamma,
                          const float* __restrict__ beta, float* __restrict__ out, int N)
{
    int node = blockIdx.x * 4 + (threadIdx.x >> 6);
    if (node >= N) return;
    int c = threadIdx.x & 63;
    float ad = ald2[node];

    int beg = rs[node], end = cur[node];
    float acc = 0.f, wsum = 0.f;
    int i = beg;
    for (; i + 1 < end; i += 2) {
        int s0 = ssrc[i], s1 = ssrc[i + 1];
        float l0 = als2[s0] + ad;
        float l1 = als2[s1] + ad;
        float hv0 = h3[s0 * 64 + c];
        float hv1 = h3[s1 * 64 + c];
        l0 = (l0 >= 0.f) ? l0 : NEG_SLOPE * l0;
        l1 = (l1 >= 0.f) ? l1 : NEG_SLOPE * l1;
        float w0 = __expf(l0), w1 = __expf(l1);
        acc += w0 * hv0; wsum += w0;
        acc += w1 * hv1; wsum += w1;
    }
    if (i < end) {
        int s0 = ssrc[i];
        float l0 = als2[s0] + ad;
        float hv0 = h3[s0 * 64 + c];
        l0 = (l0 >= 0.f) ? l0 : NEG_SLOPE * l0;
        float w0 = __expf(l0);
        acc += w0 * hv0; wsum += w0;
    }
    float o = acc / (wsum + 1e-16f) + b2[c];

    float s = o;
#pragma unroll
    for (int m = 32; m >= 1; m >>= 1) s += __shfl_xor(s, m);
    float mu = s * (1.f / 64.f);
    float dv = o - mu;
    float v = dv * dv;
#pragma unroll
    for (int m = 32; m >= 1; m >>= 1) v += __shfl_xor(v, m);
    v *= (1.f / 64.f);
    out[(size_t)node * 64 + c] = dv * rsqrtf(v + 1e-5f) * gamma[c] + beta[c];
}

extern "C" void kernel_launch(void* const* d_in, const int* in_sizes, int n_in,
                              void* d_out, int out_size, void* d_ws, size_t ws_size,
                              hipStream_t stream) {
    const float* x        = (const float*)d_in[0];
    const int*   ei       = (const int*)  d_in[1];
    const int*   type_ids = (const int*)  d_in[2];
    const float* type_emb = (const float*)d_in[3];
    const float* W1       = (const float*)d_in[4];
    const float* a_src1   = (const float*)d_in[5];
    const float* a_dst1   = (const float*)d_in[6];
    const float* b1       = (const float*)d_in[7];
    const float* W2       = (const float*)d_in[8];
    const float* a_src2   = (const float*)d_in[9];
    const float* a_dst2   = (const float*)d_in[10];
    const float* b2       = (const float*)d_in[11];
    const float* gamma    = (const float*)d_in[12];
    const float* beta     = (const float*)d_in[13];

    int N = in_sizes[0] / 5;
    int E = in_sizes[1] / 2;
    int EV = E + N;

    // Workspace layout
    float* bufA = (float*)d_ws;               // h1, then h3   [N*64]
    float* bufB = bufA + (size_t)N * 64;      // h2            [N*64]
    float* als1 = bufB + (size_t)N * 64;      // [2N]
    float* ald1 = als1 + (size_t)N * 2;       // [2N]
    float* als2 = ald1 + (size_t)N * 2;       // [N]
    float* ald2 = als2 + (size_t)N;           // [N]
    int*   deg  = (int*)(ald2 + (size_t)N);   // [N]
    int*   rs   = deg + N;                    // [N] row starts
    int*   cur  = rs + N;                     // [N] cursors -> row ends
    int*   bsum = cur + N;                    // [1024]
    int*   btop = bsum + 1024;                // [1024]
    int*   ssrc = btop + 1024;                // [EV] sorted-by-dst src ids

    dim3 tb(256);
    dim3 nb((N + 3) / 4);
    int NB = (N + 1023) / 1024;

    // Node features + layer-1 logits
    k_node1<<<nb, tb, 0, stream>>>(x, type_ids, type_emb, W1, a_src1, a_dst1,
                                   bufA, als1, ald1, N);

    // CSR build (dst-sorted)
    k_initdeg<<<dim3((N + 255) / 256), tb, 0, stream>>>(deg, N);
    k_hist<<<dim3((E + 255) / 256), tb, 0, stream>>>(ei, deg, E);
    k_scan_block<<<dim3(NB), dim3(1024), 0, stream>>>(deg, rs, bsum, N);
    k_scan_tops<<<dim3(1), dim3(1024), 0, stream>>>(bsum, btop, NB);
    k_scan_add<<<dim3((N + 255) / 256), tb, 0, stream>>>(rs, cur, btop, N);
    k_scatter<<<dim3((EV + 255) / 256), tb, 0, stream>>>(ei, cur, ssrc, E, N);

    // Layer 1 aggregate -> h2
    k_gather1<<<nb, tb, 0, stream>>>(rs, cur, ssrc, bufA, als1, ald1, b1, bufB, N);
    // Projection + layer-2 logits
    k_node2<<<nb, tb, 0, stream>>>(bufB, W2, a_src2, a_dst2, bufA, als2, ald2, N);
    // Layer 2 aggregate + LayerNorm -> out
    k_gather2<<<nb, tb, 0, stream>>>(rs, cur, ssrc, bufA, als2, ald2, b2, gamma, beta,
                                     (float*)d_out, N);
}